// Round 1
// baseline (774.946 us; speedup 1.0000x reference)
//
#include <hip/hip_runtime.h>
#include <hip/hip_fp16.h>

#define RANK   64
#define VOCAB  32768
#define BATCH  2048
#define SEQLEN 256

typedef unsigned short ushort_t;
typedef __attribute__((ext_vector_type(8))) unsigned short ushort8; // 16B = 8 halves

// ---------------------------------------------------------------------------
// Kernel 1: ws[v][g][s][k] = (half)( core[8g+k][v][s]^2 )
// Output chunk o = (v*8+g)*64 + s  -> one ushort8 (16B) per thread.
// Reads: for fixed (v,g,k), consecutive s -> 256B coalesced.
// ---------------------------------------------------------------------------
__global__ __launch_bounds__(256) void squash_kernel(const float* __restrict__ core,
                                                     ushort8* __restrict__ ws8) {
    int o = blockIdx.x * 256 + threadIdx.x;
    int v = o >> 9;
    int g = (o >> 6) & 7;
    int s = o & 63;
    ushort8 outv;
#pragma unroll
    for (int k = 0; k < 8; ++k) {
        int r = g * 8 + k;
        float c = core[((size_t)r * VOCAB + v) * RANK + s];
        __half h = __float2half(c * c);
        outv[k] = __builtin_bit_cast(unsigned short, h);
    }
    ws8[o] = outv;
}

// ---------------------------------------------------------------------------
// One recurrence step: lane s computes l_new[s] = sum_r l[r] * M[r,s].
// buf[g] holds M[8g..8g+7, lane] as 8 halves. l[r] broadcast via v_readlane
// with literal lane index (fully unrolled).
// ---------------------------------------------------------------------------
__device__ __forceinline__ float mps_step(float l, const ushort8 buf[8]) {
    float acc[4] = {0.f, 0.f, 0.f, 0.f};
#pragma unroll
    for (int g = 0; g < 8; ++g) {
        ushort8 m = buf[g];
#pragma unroll
        for (int k = 0; k < 8; ++k) {
            const int r = g * 8 + k;
            float lr = __uint_as_float(
                __builtin_amdgcn_readlane(__float_as_uint(l), r));
            unsigned short ub = m[k];
            __half h = __builtin_bit_cast(__half, ub);
            float mv = __half2float(h);
            acc[k & 3] = fmaf(lr, mv, acc[k & 3]);
        }
    }
    return (acc[0] + acc[1]) + (acc[2] + acc[3]);
}

// ---------------------------------------------------------------------------
// Kernel 2: one wave per batch element. Double-buffered matrix prefetch
// (token t+1's 8KB issued before computing token t).
// ---------------------------------------------------------------------------
__global__ __launch_bounds__(256) void mps_fp16_kernel(const int* __restrict__ y,
                                                       const float* __restrict__ alpha,
                                                       const float* __restrict__ beta,
                                                       const ushort8* __restrict__ ws8,
                                                       float* __restrict__ out) {
    int b    = (blockIdx.x * 256 + threadIdx.x) >> 6;
    int lane = threadIdx.x & 63;
    const int* yrow = y + (size_t)b * SEQLEN;

    float a = alpha[lane];
    float l = a * a;

    ushort8 bufA[8], bufB[8];

    int tok0 = __builtin_amdgcn_readfirstlane(yrow[0]);
    {
        const ushort8* p = ws8 + (size_t)tok0 * 512 + lane;
#pragma unroll
        for (int g = 0; g < 8; ++g) bufA[g] = p[g * 64];
    }

#pragma unroll 1
    for (int t = 0; t < SEQLEN; t += 2) {
        int tok1 = __builtin_amdgcn_readfirstlane(yrow[t + 1]);
        {
            const ushort8* p = ws8 + (size_t)tok1 * 512 + lane;
#pragma unroll
            for (int g = 0; g < 8; ++g) bufB[g] = p[g * 64];
        }
        l = mps_step(l, bufA);

        int tok2 = (t + 2 < SEQLEN) ? yrow[t + 2] : 0;
        tok2 = __builtin_amdgcn_readfirstlane(tok2);
        {
            const ushort8* p = ws8 + (size_t)tok2 * 512 + lane;
#pragma unroll
            for (int g = 0; g < 8; ++g) bufA[g] = p[g * 64];
        }
        l = mps_step(l, bufB);
    }

    float bb = beta[lane];
    float v  = l * bb * bb;
#pragma unroll
    for (int off = 32; off > 0; off >>= 1) v += __shfl_xor(v, off, 64);
    if (lane == 0) out[b] = v;
}

// ---------------------------------------------------------------------------
// Fallback (exact f32, direct gather from core) if ws is too small.
// ---------------------------------------------------------------------------
__global__ __launch_bounds__(256) void mps_f32_kernel(const int* __restrict__ y,
                                                      const float* __restrict__ alpha,
                                                      const float* __restrict__ beta,
                                                      const float* __restrict__ core,
                                                      float* __restrict__ out) {
    int b    = (blockIdx.x * 256 + threadIdx.x) >> 6;
    int lane = threadIdx.x & 63;
    const int* yrow = y + (size_t)b * SEQLEN;

    float a = alpha[lane];
    float l = a * a;

#pragma unroll 1
    for (int t = 0; t < SEQLEN; ++t) {
        int tok = __builtin_amdgcn_readfirstlane(yrow[t]);
        const float* p = core + (size_t)tok * RANK + lane;
        float acc[4] = {0.f, 0.f, 0.f, 0.f};
#pragma unroll
        for (int r = 0; r < RANK; ++r) {
            float m  = p[(size_t)r * (VOCAB * RANK)];
            float lr = __uint_as_float(
                __builtin_amdgcn_readlane(__float_as_uint(l), r));
            acc[r & 3] = fmaf(lr, m * m, acc[r & 3]);
        }
        l = (acc[0] + acc[1]) + (acc[2] + acc[3]);
    }

    float bb = beta[lane];
    float v  = l * bb * bb;
#pragma unroll
    for (int off = 32; off > 0; off >>= 1) v += __shfl_xor(v, off, 64);
    if (lane == 0) out[b] = v;
}

extern "C" void kernel_launch(void* const* d_in, const int* in_sizes, int n_in,
                              void* d_out, int out_size, void* d_ws, size_t ws_size,
                              hipStream_t stream) {
    const int*   y     = (const int*)d_in[0];
    const float* alpha = (const float*)d_in[1];
    const float* beta  = (const float*)d_in[2];
    const float* core  = (const float*)d_in[3];
    float*       out   = (float*)d_out;

    const size_t need = (size_t)VOCAB * RANK * RANK * sizeof(unsigned short); // 256 MiB

    if (ws_size >= need) {
        // 16.7M output chunks of 16B, 256 threads/block
        int chunks = VOCAB * 8 * 64;
        squash_kernel<<<chunks / 256, 256, 0, stream>>>(core, (ushort8*)d_ws);
        mps_fp16_kernel<<<(BATCH * 64) / 256, 256, 0, stream>>>(
            y, alpha, beta, (const ushort8*)d_ws, out);
    } else {
        mps_f32_kernel<<<(BATCH * 64) / 256, 256, 0, stream>>>(
            y, alpha, beta, core, out);
    }
}